// Round 8
// baseline (3740.860 us; speedup 1.0000x reference)
//
#include <hip/hip_runtime.h>
#include <math.h>

#define S_LEN 16
#define BSZ   64
#define NN    10000
#define LAT   128
#define DH    257
#define KTAB  1024
#define CSTRIDE (KTAB + 8)    // costab leading dim
#define FSTRIDE (KTAB + 4)    // ftab leading dim
#define NTILE2 32
#define NTILES2 313           // ceil(10000/32)
#define MSTR 36               // memT leading-dim pad
#define SCALE 0.08838834764831845f
#define NEG1E9 -1000000000.0f

// ================= setup S1: transposes + costab + wv_out/vconst/qconst + detect ============
__global__ __launch_bounds__(256) void setup_all_kernel(
    const float* __restrict__ W_ih, const float* __restrict__ W_hh,
    const float* __restrict__ tw, const float* __restrict__ tb_,
    const float* __restrict__ Wq, const float* __restrict__ bq,
    const float* __restrict__ Wv, const float* __restrict__ bv,
    const float* __restrict__ W_out, const float* __restrict__ b_out,
    const int* __restrict__ mask,
    float* __restrict__ W_ihT, float* __restrict__ W_hhT,
    float* __restrict__ costab, float* __restrict__ wv_out, float* __restrict__ vconst,
    float* __restrict__ qconst, int* __restrict__ modep) {
    int blk = blockIdx.x, tid = threadIdx.x;
    if (blk < 256) {
        int gtid = blk * 256 + tid;
        const int GS = 256 * 256;
        for (int i = gtid; i < 129 * 384; i += GS) { int d = i / 384, j = i % 384; W_ihT[i] = W_ih[j * 129 + d]; }
        for (int i = gtid; i < 128 * 384; i += GS) { int l = i / 384, j = i % 384; W_hhT[i] = W_hh[j * 128 + l]; }
        for (int p = gtid; p <= KTAB; p += GS) {
            float tv = (float)p * (1.0f / KTAB);
            for (int l = 0; l < 128; ++l) costab[l * CSTRIDE + p] = __cosf(tv * tw[l] + tb_[l]);
        }
    } else {
        // wv_out = Wv @ W_out ; vconst
        for (int d = tid; d < DH; d += 256) {
            float a = 0.f;
            for (int j = 0; j < LAT; ++j) a += Wv[d * LAT + j] * W_out[j];
            wv_out[d] = a;
        }
        if (tid == 0) {
            float a = b_out[0];
            for (int j = 0; j < LAT; ++j) a += bv[j] * W_out[j];
            *vconst = a;
        }
        // qconst[l] = bq[l] + sum_j cos(tb_j) * Wq[(129+j), l]
        if (tid < 128) {
            float a = bq[tid];
            for (int j = 0; j < 128; ++j) a += __cosf(tb_[j]) * Wq[(129 + j) * LAT + tid];
            qconst[tid] = a;
        }
        // detect
        __shared__ int hasHigh, hasFloat;
        if (tid == 0) { hasHigh = 0; hasFloat = 0; }
        __syncthreads();
        for (int i = tid; i < 4096; i += 256) {
            int v = mask[i];
            if ((unsigned)v > 1u) atomicOr(&hasHigh, 1);
            if (v == 0x3F800000) atomicOr(&hasFloat, 1);
        }
        __syncthreads();
        if (tid == 0) *modep = hasFloat ? 2 : (hasHigh ? 1 : 0);
    }
}

// ================= setup S2: BT = (Wk @ Wq[1:129]^T)^T, uc, kw0, abk, scalars ===============
__global__ __launch_bounds__(256) void setup2_kernel(
    const float* __restrict__ Wk, const float* __restrict__ Wq,
    const float* __restrict__ bk, const float* __restrict__ qconst,
    float* __restrict__ BT, float* __restrict__ uc, float* __restrict__ kw0,
    float* __restrict__ abk, float* __restrict__ scal) {
    int blk = blockIdx.x, tid = threadIdx.x;
    __shared__ float vrow[128];
    if (blk < 128) {            // BT row l: BT[l*260+d] = sum_j Wk[d,j] * Wq[1+l, j]
        int l = blk;
        if (tid < 128) vrow[tid] = Wq[(1 + l) * LAT + tid];
        __syncthreads();
        for (int d = tid; d < DH; d += 256) {
            const float* wkr = Wk + d * LAT;
            float a = 0.f;
#pragma unroll 4
            for (int j = 0; j < 128; ++j) a += wkr[j] * vrow[j];
            BT[l * 260 + d] = a;
        }
    } else if (blk == 128) {    // uc = Wk @ qconst
        if (tid < 128) vrow[tid] = qconst[tid];
        __syncthreads();
        for (int d = tid; d < DH; d += 256) {
            const float* wkr = Wk + d * LAT;
            float a = 0.f;
#pragma unroll 4
            for (int j = 0; j < 128; ++j) a += wkr[j] * vrow[j];
            uc[d] = a;
        }
    } else if (blk == 129) {    // kw0 = Wk @ Wq[0,:]
        if (tid < 128) vrow[tid] = Wq[tid];
        __syncthreads();
        for (int d = tid; d < DH; d += 256) {
            const float* wkr = Wk + d * LAT;
            float a = 0.f;
#pragma unroll 4
            for (int j = 0; j < 128; ++j) a += wkr[j] * vrow[j];
            kw0[d] = a;
        }
    } else {                    // abk[l] = Wq[1+l,:].bk ; scal = {qcbk, wq0bk}
        if (tid < 128) vrow[tid] = bk[tid];
        __syncthreads();
        if (tid < 128) {
            const float* wqr = Wq + (1 + tid) * LAT;
            float a = 0.f;
#pragma unroll 4
            for (int j = 0; j < 128; ++j) a += wqr[j] * vrow[j];
            abk[tid] = a;
        } else if (tid == 128) {
            float a = 0.f;
            for (int j = 0; j < 128; ++j) a += qconst[j] * bk[j];
            scal[0] = a;
        } else if (tid == 129) {
            float a = 0.f;
            for (int j = 0; j < 128; ++j) a += Wq[j] * bk[j];
            scal[1] = a;
        }
    }
}

// ================= GRU one row with 256 threads, uses caller's 1028-float sm =================
__device__ __forceinline__ void do_gru_row256(int r, int tid2, int s,
    const float* __restrict__ x, const float* __restrict__ t,
    const int* __restrict__ source, const int* __restrict__ target,
    const float* __restrict__ tw, const float* __restrict__ tb_,
    const float* __restrict__ W_ihT, const float* __restrict__ W_hhT,
    const float* __restrict__ b_ih, const float* __restrict__ b_hh,
    const float* __restrict__ mem, float* __restrict__ newh, float* sm) {
    float* msg = sm;          // 132
    float* h   = sm + 132;    // 128
    float* gi3 = sm + 260;    // 384
    float* gh3 = sm + 644;    // 384
    int b = r & 63;
    int idx = (r < 64) ? source[s * BSZ + b] : target[s * BSZ + b];
    const float* xs = x + (size_t)(s * BSZ + b) * NN;
    const float* ts = t + (size_t)(s * BSZ + b) * NN;
    if (tid2 == 0) msg[0] = xs[idx];
    if (tid2 < 128) {
        float tv = ts[idx];
        msg[1 + tid2] = __cosf(tv * tw[tid2] + tb_[tid2]);
        h[tid2] = mem[(size_t)idx * LAT + tid2];
    }
    __syncthreads();
    if (tid2 < 128) {
        int j = tid2;
        float a0 = b_ih[j], a1 = b_ih[128 + j], a2 = b_ih[256 + j];
#pragma unroll 4
        for (int d = 0; d < 129; ++d) {
            float m = msg[d];
            const float* col = W_ihT + d * 384;
            a0 += m * col[j]; a1 += m * col[128 + j]; a2 += m * col[256 + j];
        }
        gi3[j] = a0; gi3[128 + j] = a1; gi3[256 + j] = a2;
    } else {
        int j = tid2 - 128;
        float a0 = b_hh[j], a1 = b_hh[128 + j], a2 = b_hh[256 + j];
#pragma unroll 4
        for (int l = 0; l < 128; ++l) {
            float hv = h[l];
            const float* col = W_hhT + l * 384;
            a0 += hv * col[j]; a1 += hv * col[128 + j]; a2 += hv * col[256 + j];
        }
        gh3[j] = a0; gh3[128 + j] = a1; gh3[256 + j] = a2;
    }
    __syncthreads();
    if (tid2 < 128) {
        int j = tid2;
        float rr = 1.f / (1.f + __expf(-(gi3[j] + gh3[j])));
        float zz = 1.f / (1.f + __expf(-(gi3[128 + j] + gh3[128 + j])));
        float nn2 = tanhf(gi3[256 + j] + rr * gh3[256 + j]);
        newh[r * LAT + j] = (1.f - zz) * nn2 + zz * h[j];
    }
}

// ================= pre: blocks 0..4 gtab, blocks 5..132 gru rows for s=0 =================
__global__ __launch_bounds__(256) void pre_kernel(
    const float* __restrict__ x, const float* __restrict__ t,
    const int* __restrict__ source, const int* __restrict__ target,
    const float* __restrict__ tw, const float* __restrict__ tb_,
    const float* __restrict__ W_ihT, const float* __restrict__ W_hhT,
    const float* __restrict__ b_ih, const float* __restrict__ b_hh,
    const float* __restrict__ mem, float* __restrict__ newh,
    const float* __restrict__ wv_out, const float* __restrict__ costab,
    float* __restrict__ gtab) {
    __shared__ __align__(16) float sm[1028];
    int blk = blockIdx.x, tid = threadIdx.x;
    if (blk < 5) {
        __shared__ float wv_s[LAT];
        if (tid < LAT) wv_s[tid] = wv_out[129 + tid];
        __syncthreads();
        int p = blk * 256 + tid;
        if (p <= KTAB) {
            float a = 0.f;
            for (int l = 0; l < 128; ++l) a += wv_s[l] * costab[l * CSTRIDE + p];
            gtab[p] = a;
        }
        return;
    }
    int r = blk - 5;
    do_gru_row256(r, tid, 0, x, t, source, target, tw, tb_,
                  W_ihT, W_hhT, b_ih, b_hh, mem, newh, sm);
}

// ================= combine partials -> logit (tid<64) =================
__device__ __forceinline__ void do_combine(const float* __restrict__ partials,
                                           const float* __restrict__ vconst,
                                           float* __restrict__ out, int ps, int tid) {
    if (tid >= 64) return;
    int b = tid;
    float M = -3.0e38f, D = 0.f, Nm = 0.f;
    const float4* pp = (const float4*)partials + b * NTILES2;
    for (int i = 0; i < NTILES2; ++i) {
        float4 p = pp[i];
        float M2 = fmaxf(M, p.x);
        float e1 = __expf(M - M2), e2 = __expf(p.x - M2);
        D = D * e1 + p.y * e2;
        Nm = Nm * e1 + p.z * e2;
        M = M2;
    }
    out[ps * BSZ + b] = Nm / D + vconst[0];
}

// ================= D1: blocks 0..63 mid (single matvec), 64 scatter, 65 combine(s-1) =========
__global__ __launch_bounds__(512) void step_a3_kernel(
    const float* __restrict__ x, const int* __restrict__ source, const int* __restrict__ target,
    const float* __restrict__ BT, const float* __restrict__ uc, const float* __restrict__ kw0,
    const float* __restrict__ abk, const float* __restrict__ scal,
    const float* __restrict__ newh, float* __restrict__ mem,
    float* __restrict__ u0_g, float* __restrict__ qbk_g, float* __restrict__ uT,
    float* __restrict__ ftab, const float* __restrict__ costab,
    const float* __restrict__ partials, const float* __restrict__ vconst,
    float* __restrict__ out, int s) {
    int blk = blockIdx.x;
    int tid = threadIdx.x;
    if (blk == 64) {
        // parallel last-writer-wins scatter
        __shared__ int idxs[128];
        __shared__ int alive[128];
        if (tid < 128) idxs[tid] = (tid < 64) ? source[s * BSZ + tid] : target[s * BSZ + (tid - 64)];
        __syncthreads();
        if (tid < 128) {
            int i2 = idxs[tid];
            int a = 1;
            for (int r2 = tid + 1; r2 < 128; ++r2)
                if (idxs[r2] == i2) { a = 0; break; }
            alive[tid] = a;
        }
        __syncthreads();
        int row = tid >> 2, q4 = tid & 3;
        if (alive[row]) {
            const float4* srcp = (const float4*)(newh + row * LAT + q4 * 32);
            float4* dstp = (float4*)(mem + (size_t)idxs[row] * LAT + q4 * 32);
#pragma unroll
            for (int j = 0; j < 8; ++j) dstp[j] = srcp[j];
        }
        return;
    }
    if (blk == 65) {
        if (s > 0) do_combine(partials, vconst, out, s - 1, tid);
        return;
    }
    int b = blk;
    __shared__ float memv[128];
    __shared__ float udt_s[128];
    __shared__ float upart[4][260];
    __shared__ float red[8];
    __shared__ __align__(16) float fpart[3 * 1024];
    __shared__ int s_last;
    __shared__ float xvs;
    if (tid < 64) {
        unsigned long long mball = __ballot(target[s * BSZ + tid] == target[s * BSZ + b]);
        if (tid == 0) {
            s_last = 63 - __builtin_clzll(mball);
            xvs = x[(size_t)(s * BSZ + b) * NN + target[s * BSZ + b]];
        }
    }
    __syncthreads();
    if (tid < 128) memv[tid] = newh[(64 + s_last) * LAT + tid];   // post-scatter mem[tg]
    __syncthreads();
    float xv = xvs;
    {   // u[d] = uc[d] + xv*kw0[d] + sum_l memv[l]*BT[l*260+d], K split 4 ways (chain 32)
        int dd = tid & 127, kc = tid >> 7;
        int l0 = kc * 32;
        for (int d = dd; d < DH; d += 128) {
            float a = 0.f;
#pragma unroll 4
            for (int l = l0; l < l0 + 32; ++l) a += memv[l] * BT[l * 260 + d];
            upart[kc][d] = a;
        }
    }
    __syncthreads();
    if (tid < 257) {
        float a = uc[tid] + xv * kw0[tid] + upart[0][tid] + upart[1][tid] + upart[2][tid] + upart[3][tid];
        if (tid == 0) u0_g[b] = a;
        else if (tid <= 128) uT[(tid - 1) * BSZ + b] = a;
        else udt_s[tid - 129] = a;
    }
    if (tid >= 448) {   // qbk = scal0 + xv*scal1 + memv.abk  (one wave, tid 448..511)
        int i = tid - 448;
        float a = memv[i] * abk[i] + memv[64 + i] * abk[64 + i];
        for (int off = 32; off; off >>= 1) a += __shfl_down(a, off, 64);
        if (i == 0) qbk_g[b] = scal[0] + xv * scal[1] + a;
    }
    __syncthreads();
    {   // ftab: 8 points/thread, L split 4 ways
        int pi = tid & 127, lc = tid >> 7;
        int l0 = lc * 32;
        float a0x = 0.f, a0y = 0.f, a0z = 0.f, a0w = 0.f;
        float a1x = 0.f, a1y = 0.f, a1z = 0.f, a1w = 0.f;
#pragma unroll 4
        for (int l = l0; l < l0 + 32; ++l) {
            float ul = udt_s[l];
            const float* cp = &costab[l * CSTRIDE + pi * 8];
            float4 c0 = *(const float4*)cp;
            float4 c1 = *(const float4*)(cp + 4);
            a0x += ul * c0.x; a0y += ul * c0.y; a0z += ul * c0.z; a0w += ul * c0.w;
            a1x += ul * c1.x; a1y += ul * c1.y; a1z += ul * c1.z; a1w += ul * c1.w;
        }
        if (lc) {
            float* fp = &fpart[(lc - 1) * 1024 + pi * 8];
            *(float4*)fp = make_float4(a0x, a0y, a0z, a0w);
            *(float4*)(fp + 4) = make_float4(a1x, a1y, a1z, a1w);
        }
        if (pi == 127) {
            float a = 0.f;
            for (int l = l0; l < l0 + 32; ++l) a += udt_s[l] * costab[l * CSTRIDE + KTAB];
            red[lc] = a;
        }
        __syncthreads();
        if (lc == 0) {
            for (int c = 0; c < 3; ++c) {
                const float* fp = &fpart[c * 1024 + pi * 8];
                a0x += fp[0]; a0y += fp[1]; a0z += fp[2]; a0w += fp[3];
                a1x += fp[4]; a1y += fp[5]; a1z += fp[6]; a1w += fp[7];
            }
            float* fo = &ftab[b * FSTRIDE + pi * 8];
            *(float4*)fo = make_float4(a0x, a0y, a0z, a0w);
            *(float4*)(fo + 4) = make_float4(a1x, a1y, a1z, a1w);
        }
        if (tid == 0) ftab[b * FSTRIDE + KTAB] = red[0] + red[1] + red[2] + red[3];
    }
}

// ================= D2: blocks 0..312 attn (32-n tiles), 313..440 gru(s+1) =================
__global__ __launch_bounds__(256) void step_b3_kernel(
    const float* __restrict__ x, const float* __restrict__ t,
    const void* __restrict__ maskp, const int* __restrict__ modep,
    const int* __restrict__ source, const int* __restrict__ target,
    const float* __restrict__ tw, const float* __restrict__ tb_,
    const float* __restrict__ W_ihT, const float* __restrict__ W_hhT,
    const float* __restrict__ b_ih, const float* __restrict__ b_hh,
    const float* __restrict__ mem, float* __restrict__ newh,
    const float* __restrict__ uT, const float* __restrict__ u0_g,
    const float* __restrict__ qbk_g, const float* __restrict__ ftab,
    const float* __restrict__ gtab, const float* __restrict__ wv_out,
    float* __restrict__ partials, int s) {
    int blk = blockIdx.x, tid = threadIdx.x;

    __shared__ float memT[64 * MSTR]; // [l_local][n], 2304
    __shared__ float uTs[64 * 68];    // [l_local][b], 4352
    __shared__ float memv_s[NTILE2];
    __shared__ float wv_s[128];
    __shared__ float u0_s[64], qbk_s[64];

    if (blk >= NTILES2) {             // gru rows for step s+1
        if (s < S_LEN - 1) {
            int r = blk - NTILES2;
            do_gru_row256(r, tid, s + 1, x, t, source, target, tw, tb_,
                          W_ihT, W_hhT, b_ih, b_hh, mem, newh, memT /*scratch*/);
        }
        return;
    }

    int tile = blk;
    int n0 = tile * NTILE2;
    int tb = tid >> 4, tn = tid & 15;
    int nvalid = NN - n0; if (nvalid > NTILE2) nvalid = NTILE2;

    if (tid < 128) wv_s[tid] = wv_out[1 + tid];
    if (tid < 64) { u0_s[tid] = u0_g[tid]; qbk_s[tid] = qbk_g[tid]; }
    if (tid < NTILE2) memv_s[tid] = 0.f;

    float acc[4][2];
#pragma unroll
    for (int i = 0; i < 4; ++i) { acc[i][0] = 0.f; acc[i][1] = 0.f; }

    for (int l0 = 0; l0 < 128; l0 += 64) {
        __syncthreads();
        {   // stage mem -> memT transposed: 32 rows, 8 l's per thread
            int row = tid & 31, lq = (tid >> 5) * 8;
            if (row < nvalid) {
                const float* mrow = mem + (size_t)(n0 + row) * LAT + l0 + lq;
                float4 a0 = *(const float4*)(mrow + 0);
                float4 a1 = *(const float4*)(mrow + 4);
                memT[(lq + 0) * MSTR + row] = a0.x; memT[(lq + 1) * MSTR + row] = a0.y;
                memT[(lq + 2) * MSTR + row] = a0.z; memT[(lq + 3) * MSTR + row] = a0.w;
                memT[(lq + 4) * MSTR + row] = a1.x; memT[(lq + 5) * MSTR + row] = a1.y;
                memT[(lq + 6) * MSTR + row] = a1.z; memT[(lq + 7) * MSTR + row] = a1.w;
            } else {
#pragma unroll
                for (int j = 0; j < 8; ++j) memT[(lq + j) * MSTR + row] = 0.f;
            }
        }
        {   // stage uT chunk -> uTs
            int bq4 = (tid & 15) * 4;
            int ll = (tid >> 4) * 4;
            for (int j = 0; j < 4; ++j) {
                float4 v = *(const float4*)&uT[(l0 + ll + j) * BSZ + bq4];
                *(float4*)&uTs[(ll + j) * 68 + bq4] = v;
            }
        }
        __syncthreads();
        if (tid < NTILE2) {   // memv partial
            float a = memv_s[tid];
            for (int l = 0; l < 64; ++l) a += wv_s[l0 + l] * memT[l * MSTR + tid];
            memv_s[tid] = a;
        }
        for (int l = 0; l < 64; ++l) {
            float4 uv = *(const float4*)&uTs[l * 68 + tb * 4];
            float2 mv = *(const float2*)&memT[l * MSTR + tn * 2];
            acc[0][0] += uv.x * mv.x; acc[0][1] += uv.x * mv.y;
            acc[1][0] += uv.y * mv.x; acc[1][1] += uv.y * mv.y;
            acc[2][0] += uv.z * mv.x; acc[2][1] += uv.z * mv.y;
            acc[3][0] += uv.w * mv.x; acc[3][1] += uv.w * mv.y;
        }
    }
    __syncthreads();

    const float c0 = wv_out[0];
    int mode = *modep;
    const int* m32 = (const int*)maskp;
    const unsigned char* m8 = (const unsigned char*)maskp;
    const float* mf = (const float*)maskp;

    float pm[4], pd[4], pn[4];
#pragma unroll
    for (int i = 0; i < 4; ++i) { pm[i] = -3.0e38f; pd[i] = 0.f; pn[i] = 0.f; }

    for (int i = 0; i < 4; ++i) {
        int b = tb * 4 + i;
        size_t base = (size_t)(s * BSZ + b) * NN + n0 + tn * 2;
        float xv2[2], tv2[2]; int msk[2], vld[2];
        if (tn * 2 + 1 < nvalid) {
            float2 xx = *(const float2*)(x + base);
            float2 tt = *(const float2*)(t + base);
            xv2[0] = xx.x; xv2[1] = xx.y;
            tv2[0] = tt.x; tv2[1] = tt.y;
            if (mode == 1) {
                unsigned short mw = *(const unsigned short*)(m8 + base);
                msk[0] = mw & 0xff; msk[1] = (mw >> 8) & 0xff;
            } else if (mode == 2) {
                float2 mm = *(const float2*)(mf + base);
                msk[0] = (mm.x != 0.f); msk[1] = (mm.y != 0.f);
            } else {
                int2 mm = *(const int2*)(m32 + base);
                msk[0] = mm.x; msk[1] = mm.y;
            }
            vld[0] = vld[1] = 1;
        } else {
            for (int j = 0; j < 2; ++j) {
                int n = tn * 2 + j;
                vld[j] = (n < nvalid);
                if (vld[j]) {
                    xv2[j] = x[base + j]; tv2[j] = t[base + j];
                    msk[j] = (mode == 1) ? (int)m8[base + j] : (mode == 2) ? (mf[base + j] != 0.f) : m32[base + j];
                } else { xv2[j] = 0.f; tv2[j] = 0.f; msk[j] = 0; }
            }
        }
        const float* ft = ftab + b * FSTRIDE;
#pragma unroll
        for (int j = 0; j < 2; ++j) {
            if (!vld[j]) continue;
            float xv = xv2[j], tv = tv2[j];
            float p = tv * (float)KTAB;
            p = fminf(fmaxf(p, 0.f), (float)KTAB - 0.001f);
            int ii = (int)p;
            float fr = p - (float)ii;
            float f0 = ft[ii];
            float fv = f0 + (ft[ii + 1] - f0) * fr;
            float g0 = gtab[ii];
            float gv = g0 + (gtab[ii + 1] - g0) * fr;
            float sc = SCALE * (xv * u0_s[b] + acc[i][j] + fv + qbk_s[b]);
            if (msk[j] == 0) sc = NEG1E9;
            float val = xv * c0 + memv_s[tn * 2 + j] + gv;
            if (sc > pm[i]) {
                float a = __expf(pm[i] - sc);
                pd[i] = pd[i] * a + 1.f;
                pn[i] = pn[i] * a + val;
                pm[i] = sc;
            } else {
                float e = __expf(sc - pm[i]);
                pd[i] += e;
                pn[i] += e * val;
            }
        }
    }
#pragma unroll
    for (int mk2 = 1; mk2 < 16; mk2 <<= 1) {
#pragma unroll
        for (int i = 0; i < 4; ++i) {
            float mo = __shfl_xor(pm[i], mk2);
            float d2 = __shfl_xor(pd[i], mk2);
            float n2 = __shfl_xor(pn[i], mk2);
            float M = fmaxf(pm[i], mo);
            float e1 = __expf(pm[i] - M), e2 = __expf(mo - M);
            pd[i] = pd[i] * e1 + d2 * e2;
            pn[i] = pn[i] * e1 + n2 * e2;
            pm[i] = M;
        }
    }
    if (tn == 0) {
#pragma unroll
        for (int i = 0; i < 4; ++i) {
            int b = tb * 4 + i;
            *(float4*)&partials[(size_t)(b * NTILES2 + tile) * 4] = make_float4(pm[i], pd[i], pn[i], 0.f);
        }
    }
}

// ================= tail combine (step 15) =================
__global__ __launch_bounds__(64) void tail_kernel(const float* __restrict__ partials,
                                                  const float* __restrict__ vconst,
                                                  float* __restrict__ out) {
    do_combine(partials, vconst, out, S_LEN - 1, threadIdx.x);
}

extern "C" void kernel_launch(void* const* d_in, const int* in_sizes, int n_in,
                              void* d_out, int out_size, void* d_ws, size_t ws_size,
                              hipStream_t stream) {
    const float* x      = (const float*)d_in[0];
    const float* t      = (const float*)d_in[1];
    const int*   source = (const int*)d_in[2];
    const int*   target = (const int*)d_in[3];
    const void*  maskp  = (const void*)d_in[4];
    const float* tw     = (const float*)d_in[5];
    const float* tb     = (const float*)d_in[6];
    const float* W_ih   = (const float*)d_in[7];
    const float* W_hh   = (const float*)d_in[8];
    const float* b_ih   = (const float*)d_in[9];
    const float* b_hh   = (const float*)d_in[10];
    const float* Wq     = (const float*)d_in[11];
    const float* bq     = (const float*)d_in[12];
    const float* Wk     = (const float*)d_in[13];
    const float* bk     = (const float*)d_in[14];
    const float* Wv     = (const float*)d_in[15];
    const float* bv     = (const float*)d_in[16];
    const float* W_out  = (const float*)d_in[17];
    const float* b_out  = (const float*)d_in[18];
    float* out = (float*)d_out;

    float* w = (float*)d_ws;
    float* mem    = w; w += (size_t)NN * LAT;        // 1,280,000
    float* newh   = w; w += 128 * LAT;               // 16,384
    float* uT     = w; w += LAT * BSZ;               // 8,192
    float* u0_g   = w; w += BSZ;
    float* qbk_g  = w; w += BSZ;
    float* ftab   = w; w += BSZ * FSTRIDE;           // 65,792
    float* gtab   = w; w += FSTRIDE;                 // 1,028
    float* costab = w; w += LAT * CSTRIDE;           // 132,096
    float* partials = w; w += (size_t)BSZ * NTILES2 * 4; // 80,128
    float* wv_out = w; w += 260;
    float* vconst = w; w += 4;
    float* W_ihT  = w; w += 129 * 384;               // 49,536
    float* W_hhT  = w; w += 128 * 384;               // 49,152
    float* BT     = w; w += 128 * 260;               // 33,280
    float* uc     = w; w += 260;
    float* kw0    = w; w += 260;
    float* abk    = w; w += 128;
    float* qconst = w; w += 128;
    float* scal   = w; w += 8;
    int*   modep  = (int*)w;

    hipMemsetAsync(mem, 0, (size_t)NN * LAT * sizeof(float), stream);
    setup_all_kernel<<<257, 256, 0, stream>>>(W_ih, W_hh, tw, tb, Wq, bq, Wv, bv, W_out, b_out,
                                              (const int*)maskp, W_ihT, W_hhT,
                                              costab, wv_out, vconst, qconst, modep);
    setup2_kernel<<<131, 256, 0, stream>>>(Wk, Wq, bk, qconst, BT, uc, kw0, abk, scal);
    pre_kernel<<<133, 256, 0, stream>>>(x, t, source, target, tw, tb,
                                        W_ihT, W_hhT, b_ih, b_hh, mem, newh,
                                        wv_out, costab, gtab);

    for (int s = 0; s < S_LEN; ++s) {
        step_a3_kernel<<<66, 512, 0, stream>>>(x, source, target, BT, uc, kw0, abk, scal,
                                               newh, mem, u0_g, qbk_g, uT, ftab, costab,
                                               partials, vconst, out, s);
        step_b3_kernel<<<NTILES2 + 128, 256, 0, stream>>>(x, t, maskp, modep, source, target,
                                                          tw, tb, W_ihT, W_hhT, b_ih, b_hh,
                                                          mem, newh, uT, u0_g, qbk_g,
                                                          ftab, gtab, wv_out, partials, s);
    }
    tail_kernel<<<1, 64, 0, stream>>>(partials, vconst, out);
}

// Round 9
// 823.489 us; speedup vs baseline: 4.5427x; 4.5427x over previous
//
#include <hip/hip_runtime.h>
#include <math.h>

#define S_LEN 16
#define BSZ   64
#define NN    10000
#define LAT   128
#define DH    257
#define KTAB  1024
#define CSTRIDE (KTAB + 8)    // costab leading dim
#define FSTRIDE (KTAB + 4)    // ftab leading dim
#define NTILE 64
#define NTILES 157            // ceil(10000/64)
#define SCALE 0.08838834764831845f
#define NEG1E9 -1000000000.0f

// ================= setup S1: transposes + costab + wv_out/vconst/qconst + detect ============
__global__ __launch_bounds__(256) void setup_all_kernel(
    const float* __restrict__ W_ih, const float* __restrict__ W_hh,
    const float* __restrict__ tw, const float* __restrict__ tb_,
    const float* __restrict__ Wq, const float* __restrict__ bq,
    const float* __restrict__ Wv, const float* __restrict__ bv,
    const float* __restrict__ W_out, const float* __restrict__ b_out,
    const int* __restrict__ mask,
    float* __restrict__ W_ihT, float* __restrict__ W_hhT,
    float* __restrict__ costab, float* __restrict__ wv_out, float* __restrict__ vconst,
    float* __restrict__ qconst, int* __restrict__ modep) {
    int blk = blockIdx.x, tid = threadIdx.x;
    if (blk < 256) {
        int gtid = blk * 256 + tid;
        const int GS = 256 * 256;
        for (int i = gtid; i < 129 * 384; i += GS) { int d = i / 384, j = i % 384; W_ihT[i] = W_ih[j * 129 + d]; }
        for (int i = gtid; i < 128 * 384; i += GS) { int l = i / 384, j = i % 384; W_hhT[i] = W_hh[j * 128 + l]; }
        for (int p = gtid; p <= KTAB; p += GS) {
            float tv = (float)p * (1.0f / KTAB);
            for (int l = 0; l < 128; ++l) costab[l * CSTRIDE + p] = __cosf(tv * tw[l] + tb_[l]);
        }
    } else {
        for (int d = tid; d < DH; d += 256) {
            float a = 0.f;
            for (int j = 0; j < LAT; ++j) a += Wv[d * LAT + j] * W_out[j];
            wv_out[d] = a;
        }
        if (tid == 0) {
            float a = b_out[0];
            for (int j = 0; j < LAT; ++j) a += bv[j] * W_out[j];
            *vconst = a;
        }
        // qconst[l] = bq[l] + sum_j cos(tb_j) * Wq[(129+j), l]
        if (tid < 128) {
            float a = bq[tid];
            for (int j = 0; j < 128; ++j) a += __cosf(tb_[j]) * Wq[(129 + j) * LAT + tid];
            qconst[tid] = a;
        }
        __shared__ int hasHigh, hasFloat;
        if (tid == 0) { hasHigh = 0; hasFloat = 0; }
        __syncthreads();
        for (int i = tid; i < 4096; i += 256) {
            int v = mask[i];
            if ((unsigned)v > 1u) atomicOr(&hasHigh, 1);
            if (v == 0x3F800000) atomicOr(&hasFloat, 1);
        }
        __syncthreads();
        if (tid == 0) *modep = hasFloat ? 2 : (hasHigh ? 1 : 0);
    }
}

// ================= setup S2: BT = (Wk @ Wq[1:129]^T)^T, uc, kw0, abk, scalars ===============
__global__ __launch_bounds__(256) void setup2_kernel(
    const float* __restrict__ Wk, const float* __restrict__ Wq,
    const float* __restrict__ bk, const float* __restrict__ qconst,
    float* __restrict__ BT, float* __restrict__ uc, float* __restrict__ kw0,
    float* __restrict__ abk, float* __restrict__ scal) {
    int blk = blockIdx.x, tid = threadIdx.x;
    __shared__ float vrow[128];
    if (blk < 128) {            // BT row l: BT[l*260+d] = sum_j Wk[d,j] * Wq[1+l, j]
        int l = blk;
        if (tid < 128) vrow[tid] = Wq[(1 + l) * LAT + tid];
        __syncthreads();
        for (int d = tid; d < DH; d += 256) {
            const float* wkr = Wk + d * LAT;
            float a = 0.f;
#pragma unroll 4
            for (int j = 0; j < 128; ++j) a += wkr[j] * vrow[j];
            BT[l * 260 + d] = a;
        }
    } else if (blk == 128) {    // uc = Wk @ qconst
        if (tid < 128) vrow[tid] = qconst[tid];
        __syncthreads();
        for (int d = tid; d < DH; d += 256) {
            const float* wkr = Wk + d * LAT;
            float a = 0.f;
#pragma unroll 4
            for (int j = 0; j < 128; ++j) a += wkr[j] * vrow[j];
            uc[d] = a;
        }
    } else if (blk == 129) {    // kw0 = Wk @ Wq[0,:]
        if (tid < 128) vrow[tid] = Wq[tid];
        __syncthreads();
        for (int d = tid; d < DH; d += 256) {
            const float* wkr = Wk + d * LAT;
            float a = 0.f;
#pragma unroll 4
            for (int j = 0; j < 128; ++j) a += wkr[j] * vrow[j];
            kw0[d] = a;
        }
    } else {                    // abk[l] = Wq[1+l,:].bk ; scal = {qconst.bk, Wq0.bk}
        if (tid < 128) vrow[tid] = bk[tid];
        __syncthreads();
        if (tid < 128) {
            const float* wqr = Wq + (1 + tid) * LAT;
            float a = 0.f;
#pragma unroll 4
            for (int j = 0; j < 128; ++j) a += wqr[j] * vrow[j];
            abk[tid] = a;
        } else if (tid == 128) {
            float a = 0.f;
            for (int j = 0; j < 128; ++j) a += qconst[j] * bk[j];
            scal[0] = a;
        } else if (tid == 129) {
            float a = 0.f;
            for (int j = 0; j < 128; ++j) a += Wq[j] * bk[j];
            scal[1] = a;
        }
    }
}

// ================= GRU one row with 256 threads, uses caller's 1028-float sm =================
__device__ __forceinline__ void do_gru_row256(int r, int tid2, int s,
    const float* __restrict__ x, const float* __restrict__ t,
    const int* __restrict__ source, const int* __restrict__ target,
    const float* __restrict__ tw, const float* __restrict__ tb_,
    const float* __restrict__ W_ihT, const float* __restrict__ W_hhT,
    const float* __restrict__ b_ih, const float* __restrict__ b_hh,
    const float* __restrict__ mem, float* __restrict__ newh, float* sm) {
    float* msg = sm;          // 132
    float* h   = sm + 132;    // 128
    float* gi3 = sm + 260;    // 384
    float* gh3 = sm + 644;    // 384
    int b = r & 63;
    int idx = (r < 64) ? source[s * BSZ + b] : target[s * BSZ + b];
    const float* xs = x + (size_t)(s * BSZ + b) * NN;
    const float* ts = t + (size_t)(s * BSZ + b) * NN;
    if (tid2 == 0) msg[0] = xs[idx];
    if (tid2 < 128) {
        float tv = ts[idx];
        msg[1 + tid2] = __cosf(tv * tw[tid2] + tb_[tid2]);
        h[tid2] = mem[(size_t)idx * LAT + tid2];
    }
    __syncthreads();
    if (tid2 < 128) {
        int j = tid2;
        float a0 = b_ih[j], a1 = b_ih[128 + j], a2 = b_ih[256 + j];
#pragma unroll 4
        for (int d = 0; d < 129; ++d) {
            float m = msg[d];
            const float* col = W_ihT + d * 384;
            a0 += m * col[j]; a1 += m * col[128 + j]; a2 += m * col[256 + j];
        }
        gi3[j] = a0; gi3[128 + j] = a1; gi3[256 + j] = a2;
    } else {
        int j = tid2 - 128;
        float a0 = b_hh[j], a1 = b_hh[128 + j], a2 = b_hh[256 + j];
#pragma unroll 4
        for (int l = 0; l < 128; ++l) {
            float hv = h[l];
            const float* col = W_hhT + l * 384;
            a0 += hv * col[j]; a1 += hv * col[128 + j]; a2 += hv * col[256 + j];
        }
        gh3[j] = a0; gh3[128 + j] = a1; gh3[256 + j] = a2;
    }
    __syncthreads();
    if (tid2 < 128) {
        int j = tid2;
        float rr = 1.f / (1.f + __expf(-(gi3[j] + gh3[j])));
        float zz = 1.f / (1.f + __expf(-(gi3[128 + j] + gh3[128 + j])));
        float nn2 = tanhf(gi3[256 + j] + rr * gh3[256 + j]);
        newh[r * LAT + j] = (1.f - zz) * nn2 + zz * h[j];
    }
}

// ================= pre: blocks 0..4 gtab, blocks 5..132 gru rows for s=0 =================
__global__ __launch_bounds__(256) void pre_kernel(
    const float* __restrict__ x, const float* __restrict__ t,
    const int* __restrict__ source, const int* __restrict__ target,
    const float* __restrict__ tw, const float* __restrict__ tb_,
    const float* __restrict__ W_ihT, const float* __restrict__ W_hhT,
    const float* __restrict__ b_ih, const float* __restrict__ b_hh,
    const float* __restrict__ mem, float* __restrict__ newh,
    const float* __restrict__ wv_out, const float* __restrict__ costab,
    float* __restrict__ gtab) {
    __shared__ __align__(16) float sm[1028];
    int blk = blockIdx.x, tid = threadIdx.x;
    if (blk < 5) {
        __shared__ float wv_s[LAT];
        if (tid < LAT) wv_s[tid] = wv_out[129 + tid];
        __syncthreads();
        int p = blk * 256 + tid;
        if (p <= KTAB) {
            float a = 0.f;
            for (int l = 0; l < 128; ++l) a += wv_s[l] * costab[l * CSTRIDE + p];
            gtab[p] = a;
        }
        return;
    }
    int r = blk - 5;
    do_gru_row256(r, tid, 0, x, t, source, target, tw, tb_,
                  W_ihT, W_hhT, b_ih, b_hh, mem, newh, sm);
}

// ================= combine partials -> logit (tid<64) =================
__device__ __forceinline__ void do_combine(const float* __restrict__ partials,
                                           const float* __restrict__ vconst,
                                           float* __restrict__ out, int ps, int tid) {
    if (tid >= 64) return;
    int b = tid;
    float M = -3.0e38f, D = 0.f, Nm = 0.f;
    const float4* pp = (const float4*)partials + b * NTILES;
    for (int i = 0; i < NTILES; ++i) {
        float4 p = pp[i];
        float M2 = fmaxf(M, p.x);
        float e1 = __expf(M - M2), e2 = __expf(p.x - M2);
        D = D * e1 + p.y * e2;
        Nm = Nm * e1 + p.z * e2;
        M = M2;
    }
    out[ps * BSZ + b] = Nm / D + vconst[0];
}

// ================= D1: blocks 0..63 mid (single matvec), 64 scatter, 65 combine(s-1) =========
__global__ __launch_bounds__(512) void step_a3_kernel(
    const float* __restrict__ x, const int* __restrict__ source, const int* __restrict__ target,
    const float* __restrict__ BT, const float* __restrict__ uc, const float* __restrict__ kw0,
    const float* __restrict__ abk, const float* __restrict__ scal,
    const float* __restrict__ newh, float* __restrict__ mem,
    float* __restrict__ u0_g, float* __restrict__ qbk_g, float* __restrict__ uT,
    float* __restrict__ ftab, const float* __restrict__ costab,
    const float* __restrict__ partials, const float* __restrict__ vconst,
    float* __restrict__ out, int s) {
    int blk = blockIdx.x;
    int tid = threadIdx.x;
    if (blk == 64) {
        // parallel last-writer-wins scatter
        __shared__ int idxs[128];
        __shared__ int alive[128];
        if (tid < 128) idxs[tid] = (tid < 64) ? source[s * BSZ + tid] : target[s * BSZ + (tid - 64)];
        __syncthreads();
        if (tid < 128) {
            int i2 = idxs[tid];
            int a = 1;
            for (int r2 = tid + 1; r2 < 128; ++r2)
                if (idxs[r2] == i2) { a = 0; break; }
            alive[tid] = a;
        }
        __syncthreads();
        int row = tid >> 2, q4 = tid & 3;
        if (alive[row]) {
            const float4* srcp = (const float4*)(newh + row * LAT + q4 * 32);
            float4* dstp = (float4*)(mem + (size_t)idxs[row] * LAT + q4 * 32);
#pragma unroll
            for (int j = 0; j < 8; ++j) dstp[j] = srcp[j];
        }
        return;
    }
    if (blk == 65) {
        if (s > 0) do_combine(partials, vconst, out, s - 1, tid);
        return;
    }
    int b = blk;
    __shared__ float memv[128];
    __shared__ float udt_s[128];
    __shared__ float upart[4][260];
    __shared__ float red[8];
    __shared__ __align__(16) float fpart[3 * 1024];
    __shared__ int s_last;
    __shared__ float xvs;
    if (tid < 64) {
        unsigned long long mball = __ballot(target[s * BSZ + tid] == target[s * BSZ + b]);
        if (tid == 0) {
            s_last = 63 - __builtin_clzll(mball);
            xvs = x[(size_t)(s * BSZ + b) * NN + target[s * BSZ + b]];
        }
    }
    __syncthreads();
    if (tid < 128) memv[tid] = newh[(64 + s_last) * LAT + tid];   // post-scatter mem[tg]
    __syncthreads();
    float xv = xvs;
    {   // u[d] = uc[d] + xv*kw0[d] + sum_l memv[l]*BT[l*260+d], K split 4 ways (chain 32)
        int dd = tid & 127, kc = tid >> 7;
        int l0 = kc * 32;
        for (int d = dd; d < DH; d += 128) {
            float a = 0.f;
#pragma unroll 4
            for (int l = l0; l < l0 + 32; ++l) a += memv[l] * BT[l * 260 + d];
            upart[kc][d] = a;
        }
    }
    __syncthreads();
    if (tid < 257) {
        float a = uc[tid] + xv * kw0[tid] + upart[0][tid] + upart[1][tid] + upart[2][tid] + upart[3][tid];
        if (tid == 0) u0_g[b] = a;
        else if (tid <= 128) uT[(tid - 1) * BSZ + b] = a;
        else udt_s[tid - 129] = a;
    }
    if (tid >= 448) {   // qbk = scal0 + xv*scal1 + memv.abk  (one wave)
        int i = tid - 448;
        float a = memv[i] * abk[i] + memv[64 + i] * abk[64 + i];
        for (int off = 32; off; off >>= 1) a += __shfl_down(a, off, 64);
        if (i == 0) qbk_g[b] = scal[0] + xv * scal[1] + a;
    }
    __syncthreads();
    {   // ftab: 8 points/thread, L split 4 ways
        int pi = tid & 127, lc = tid >> 7;
        int l0 = lc * 32;
        float a0x = 0.f, a0y = 0.f, a0z = 0.f, a0w = 0.f;
        float a1x = 0.f, a1y = 0.f, a1z = 0.f, a1w = 0.f;
#pragma unroll 4
        for (int l = l0; l < l0 + 32; ++l) {
            float ul = udt_s[l];
            const float* cp = &costab[l * CSTRIDE + pi * 8];
            float4 c0 = *(const float4*)cp;
            float4 c1 = *(const float4*)(cp + 4);
            a0x += ul * c0.x; a0y += ul * c0.y; a0z += ul * c0.z; a0w += ul * c0.w;
            a1x += ul * c1.x; a1y += ul * c1.y; a1z += ul * c1.z; a1w += ul * c1.w;
        }
        if (lc) {
            float* fp = &fpart[(lc - 1) * 1024 + pi * 8];
            *(float4*)fp = make_float4(a0x, a0y, a0z, a0w);
            *(float4*)(fp + 4) = make_float4(a1x, a1y, a1z, a1w);
        }
        if (pi == 127) {
            float a = 0.f;
            for (int l = l0; l < l0 + 32; ++l) a += udt_s[l] * costab[l * CSTRIDE + KTAB];
            red[lc] = a;
        }
        __syncthreads();
        if (lc == 0) {
            for (int c = 0; c < 3; ++c) {
                const float* fp = &fpart[c * 1024 + pi * 8];
                a0x += fp[0]; a0y += fp[1]; a0z += fp[2]; a0w += fp[3];
                a1x += fp[4]; a1y += fp[5]; a1z += fp[6]; a1w += fp[7];
            }
            float* fo = &ftab[b * FSTRIDE + pi * 8];
            *(float4*)fo = make_float4(a0x, a0y, a0z, a0w);
            *(float4*)(fo + 4) = make_float4(a1x, a1y, a1z, a1w);
        }
        if (tid == 0) ftab[b * FSTRIDE + KTAB] = red[0] + red[1] + red[2] + red[3];
    }
}

// ================= D2: blocks 0..156 attn (R7 attn verbatim, 256 thr), 157..284 gru(s+1) ====
__global__ __launch_bounds__(256) void step_b2_kernel(
    const float* __restrict__ x, const float* __restrict__ t,
    const void* __restrict__ maskp, const int* __restrict__ modep,
    const int* __restrict__ source, const int* __restrict__ target,
    const float* __restrict__ tw, const float* __restrict__ tb_,
    const float* __restrict__ W_ihT, const float* __restrict__ W_hhT,
    const float* __restrict__ b_ih, const float* __restrict__ b_hh,
    const float* __restrict__ mem, float* __restrict__ newh,
    const float* __restrict__ uT, const float* __restrict__ u0_g,
    const float* __restrict__ qbk_g, const float* __restrict__ ftab,
    const float* __restrict__ gtab, const float* __restrict__ wv_out,
    float* __restrict__ partials, int s) {
    int blk = blockIdx.x, tid = threadIdx.x;

    __shared__ float memT[64 * 72];   // [l_local][n], stride 72
    __shared__ float uTs[64 * 68];    // [l_local][b], stride 68
    __shared__ float memv_s[64];
    __shared__ float wv_s[128];
    __shared__ float u0_s[64], qbk_s[64];

    if (blk >= NTILES) {              // gru rows for step s+1
        if (s < S_LEN - 1) {
            int r = blk - NTILES;
            do_gru_row256(r, tid, s + 1, x, t, source, target, tw, tb_,
                          W_ihT, W_hhT, b_ih, b_hh, mem, newh, memT /*1028 floats scratch*/);
        }
        return;
    }

    int tile = blk;
    int n0 = tile * NTILE;
    int tb = tid >> 4, tn = tid & 15;
    int nvalid = NN - n0; if (nvalid > NTILE) nvalid = NTILE;

    if (tid < 128) wv_s[tid] = wv_out[1 + tid];
    if (tid < 64) { u0_s[tid] = u0_g[tid]; qbk_s[tid] = qbk_g[tid]; memv_s[tid] = 0.f; }

    float acc[4][4];
#pragma unroll
    for (int i = 0; i < 4; ++i)
#pragma unroll
        for (int j = 0; j < 4; ++j) acc[i][j] = 0.f;

    for (int l0 = 0; l0 < 128; l0 += 64) {
        __syncthreads();
        {   // stage mem -> memT transposed
            int n_l = tid & 63, lq = (tid >> 6) * 16;
            if (n_l < nvalid) {
                const float* mrow = mem + (size_t)(n0 + n_l) * LAT + l0 + lq;
                float4 a0 = *(const float4*)(mrow + 0);
                float4 a1 = *(const float4*)(mrow + 4);
                float4 a2 = *(const float4*)(mrow + 8);
                float4 a3 = *(const float4*)(mrow + 12);
                memT[(lq + 0) * 72 + n_l] = a0.x; memT[(lq + 1) * 72 + n_l] = a0.y;
                memT[(lq + 2) * 72 + n_l] = a0.z; memT[(lq + 3) * 72 + n_l] = a0.w;
                memT[(lq + 4) * 72 + n_l] = a1.x; memT[(lq + 5) * 72 + n_l] = a1.y;
                memT[(lq + 6) * 72 + n_l] = a1.z; memT[(lq + 7) * 72 + n_l] = a1.w;
                memT[(lq + 8) * 72 + n_l] = a2.x; memT[(lq + 9) * 72 + n_l] = a2.y;
                memT[(lq + 10) * 72 + n_l] = a2.z; memT[(lq + 11) * 72 + n_l] = a2.w;
                memT[(lq + 12) * 72 + n_l] = a3.x; memT[(lq + 13) * 72 + n_l] = a3.y;
                memT[(lq + 14) * 72 + n_l] = a3.z; memT[(lq + 15) * 72 + n_l] = a3.w;
            } else {
                for (int j = 0; j < 16; ++j) memT[(lq + j) * 72 + n_l] = 0.f;
            }
        }
        {   // stage uT chunk -> uTs
            int bq4 = (tid & 15) * 4;
            int ll = (tid >> 4) * 4;
            for (int j = 0; j < 4; ++j) {
                float4 v = *(const float4*)&uT[(l0 + ll + j) * BSZ + bq4];
                *(float4*)&uTs[(ll + j) * 68 + bq4] = v;
            }
        }
        __syncthreads();
        if (tid < 64) {   // memv partial
            float a = memv_s[tid];
            for (int l = 0; l < 64; ++l) a += wv_s[l0 + l] * memT[l * 72 + tid];
            memv_s[tid] = a;
        }
        for (int l = 0; l < 64; ++l) {
            float4 uv = *(const float4*)&uTs[l * 68 + tb * 4];
            float4 mv = *(const float4*)&memT[l * 72 + tn * 4];
            acc[0][0] += uv.x * mv.x; acc[0][1] += uv.x * mv.y; acc[0][2] += uv.x * mv.z; acc[0][3] += uv.x * mv.w;
            acc[1][0] += uv.y * mv.x; acc[1][1] += uv.y * mv.y; acc[1][2] += uv.y * mv.z; acc[1][3] += uv.y * mv.w;
            acc[2][0] += uv.z * mv.x; acc[2][1] += uv.z * mv.y; acc[2][2] += uv.z * mv.z; acc[2][3] += uv.z * mv.w;
            acc[3][0] += uv.w * mv.x; acc[3][1] += uv.w * mv.y; acc[3][2] += uv.w * mv.z; acc[3][3] += uv.w * mv.w;
        }
    }
    __syncthreads();

    const float c0 = wv_out[0];
    int mode = *modep;
    const int* m32 = (const int*)maskp;
    const unsigned char* m8 = (const unsigned char*)maskp;
    const float* mf = (const float*)maskp;

    float pm[4], pd[4], pn[4];
#pragma unroll
    for (int i = 0; i < 4; ++i) { pm[i] = -3.0e38f; pd[i] = 0.f; pn[i] = 0.f; }

    for (int i = 0; i < 4; ++i) {
        int b = tb * 4 + i;
        size_t base = (size_t)(s * BSZ + b) * NN + n0 + tn * 4;
        float xv4[4], tv4[4]; int msk[4], vld[4];
        if (tn * 4 + 3 < nvalid) {
            float4 xx = *(const float4*)(x + base);
            float4 tt = *(const float4*)(t + base);
            xv4[0] = xx.x; xv4[1] = xx.y; xv4[2] = xx.z; xv4[3] = xx.w;
            tv4[0] = tt.x; tv4[1] = tt.y; tv4[2] = tt.z; tv4[3] = tt.w;
            if (mode == 1) {
                unsigned mw = *(const unsigned*)(m8 + base);
                msk[0] = mw & 0xff; msk[1] = (mw >> 8) & 0xff; msk[2] = (mw >> 16) & 0xff; msk[3] = (mw >> 24) & 0xff;
            } else if (mode == 2) {
                float4 mm = *(const float4*)(mf + base);
                msk[0] = (mm.x != 0.f); msk[1] = (mm.y != 0.f); msk[2] = (mm.z != 0.f); msk[3] = (mm.w != 0.f);
            } else {
                int4 mm = *(const int4*)(m32 + base);
                msk[0] = mm.x; msk[1] = mm.y; msk[2] = mm.z; msk[3] = mm.w;
            }
            vld[0] = vld[1] = vld[2] = vld[3] = 1;
        } else {
            for (int j = 0; j < 4; ++j) {
                int n = tn * 4 + j;
                vld[j] = (n < nvalid);
                if (vld[j]) {
                    xv4[j] = x[base + j]; tv4[j] = t[base + j];
                    msk[j] = (mode == 1) ? (int)m8[base + j] : (mode == 2) ? (mf[base + j] != 0.f) : m32[base + j];
                } else { xv4[j] = 0.f; tv4[j] = 0.f; msk[j] = 0; }
            }
        }
        const float* ft = ftab + b * FSTRIDE;
#pragma unroll
        for (int j = 0; j < 4; ++j) {
            if (!vld[j]) continue;
            float xv = xv4[j], tv = tv4[j];
            float p = tv * (float)KTAB;
            p = fminf(fmaxf(p, 0.f), (float)KTAB - 0.001f);
            int ii = (int)p;
            float fr = p - (float)ii;
            float f0 = ft[ii];
            float fv = f0 + (ft[ii + 1] - f0) * fr;
            float g0 = gtab[ii];
            float gv = g0 + (gtab[ii + 1] - g0) * fr;
            float sc = SCALE * (xv * u0_s[b] + acc[i][j] + fv + qbk_s[b]);
            if (msk[j] == 0) sc = NEG1E9;
            float val = xv * c0 + memv_s[tn * 4 + j] + gv;
            if (sc > pm[i]) {
                float a = __expf(pm[i] - sc);
                pd[i] = pd[i] * a + 1.f;
                pn[i] = pn[i] * a + val;
                pm[i] = sc;
            } else {
                float e = __expf(sc - pm[i]);
                pd[i] += e;
                pn[i] += e * val;
            }
        }
    }
#pragma unroll
    for (int mk2 = 1; mk2 < 16; mk2 <<= 1) {
#pragma unroll
        for (int i = 0; i < 4; ++i) {
            float mo = __shfl_xor(pm[i], mk2);
            float d2 = __shfl_xor(pd[i], mk2);
            float n2 = __shfl_xor(pn[i], mk2);
            float M = fmaxf(pm[i], mo);
            float e1 = __expf(pm[i] - M), e2 = __expf(mo - M);
            pd[i] = pd[i] * e1 + d2 * e2;
            pn[i] = pn[i] * e1 + n2 * e2;
            pm[i] = M;
        }
    }
    if (tn == 0) {
#pragma unroll
        for (int i = 0; i < 4; ++i) {
            int b = tb * 4 + i;
            *(float4*)&partials[(size_t)(b * NTILES + tile) * 4] = make_float4(pm[i], pd[i], pn[i], 0.f);
        }
    }
}

// ================= tail combine (step 15) =================
__global__ __launch_bounds__(64) void tail_kernel(const float* __restrict__ partials,
                                                  const float* __restrict__ vconst,
                                                  float* __restrict__ out) {
    do_combine(partials, vconst, out, S_LEN - 1, threadIdx.x);
}

extern "C" void kernel_launch(void* const* d_in, const int* in_sizes, int n_in,
                              void* d_out, int out_size, void* d_ws, size_t ws_size,
                              hipStream_t stream) {
    const float* x      = (const float*)d_in[0];
    const float* t      = (const float*)d_in[1];
    const int*   source = (const int*)d_in[2];
    const int*   target = (const int*)d_in[3];
    const void*  maskp  = (const void*)d_in[4];
    const float* tw     = (const float*)d_in[5];
    const float* tb     = (const float*)d_in[6];
    const float* W_ih   = (const float*)d_in[7];
    const float* W_hh   = (const float*)d_in[8];
    const float* b_ih   = (const float*)d_in[9];
    const float* b_hh   = (const float*)d_in[10];
    const float* Wq     = (const float*)d_in[11];
    const float* bq     = (const float*)d_in[12];
    const float* Wk     = (const float*)d_in[13];
    const float* bk     = (const float*)d_in[14];
    const float* Wv     = (const float*)d_in[15];
    const float* bv     = (const float*)d_in[16];
    const float* W_out  = (const float*)d_in[17];
    const float* b_out  = (const float*)d_in[18];
    float* out = (float*)d_out;

    float* w = (float*)d_ws;
    float* mem    = w; w += (size_t)NN * LAT;        // 1,280,000
    float* newh   = w; w += 128 * LAT;               // 16,384
    float* uT     = w; w += LAT * BSZ;               // 8,192
    float* u0_g   = w; w += BSZ;
    float* qbk_g  = w; w += BSZ;
    float* ftab   = w; w += BSZ * FSTRIDE;           // 65,792
    float* gtab   = w; w += FSTRIDE;                 // 1,028
    float* costab = w; w += LAT * CSTRIDE;           // 132,096
    float* partials = w; w += (size_t)BSZ * NTILES * 4; // 40,192
    float* wv_out = w; w += 260;
    float* vconst = w; w += 4;
    float* W_ihT  = w; w += 129 * 384;               // 49,536
    float* W_hhT  = w; w += 128 * 384;               // 49,152
    float* BT     = w; w += 128 * 260;               // 33,280
    float* uc     = w; w += 260;
    float* kw0    = w; w += 260;
    float* abk    = w; w += 128;
    float* qconst = w; w += 128;
    float* scal   = w; w += 8;
    int*   modep  = (int*)w;

    hipMemsetAsync(mem, 0, (size_t)NN * LAT * sizeof(float), stream);
    setup_all_kernel<<<257, 256, 0, stream>>>(W_ih, W_hh, tw, tb, Wq, bq, Wv, bv, W_out, b_out,
                                              (const int*)maskp, W_ihT, W_hhT,
                                              costab, wv_out, vconst, qconst, modep);
    setup2_kernel<<<131, 256, 0, stream>>>(Wk, Wq, bk, qconst, BT, uc, kw0, abk, scal);
    pre_kernel<<<133, 256, 0, stream>>>(x, t, source, target, tw, tb,
                                        W_ihT, W_hhT, b_ih, b_hh, mem, newh,
                                        wv_out, costab, gtab);

    for (int s = 0; s < S_LEN; ++s) {
        step_a3_kernel<<<66, 512, 0, stream>>>(x, source, target, BT, uc, kw0, abk, scal,
                                               newh, mem, u0_g, qbk_g, uT, ftab, costab,
                                               partials, vconst, out, s);
        step_b2_kernel<<<NTILES + 128, 256, 0, stream>>>(x, t, maskp, modep, source, target,
                                                         tw, tb, W_ihT, W_hhT, b_ih, b_hh,
                                                         mem, newh, uT, u0_g, qbk_g,
                                                         ftab, gtab, wv_out, partials, s);
    }
    tail_kernel<<<1, 64, 0, stream>>>(partials, vconst, out);
}